// Round 1
// baseline (9341.566 us; speedup 1.0000x reference)
//
#include <hip/hip_runtime.h>
#include <math.h>

#define TT 2048
#define EE 512
#define HDD 512
#define TAGS 32
#define STARTT 30
#define STOPP 31
#define NEGV -10000.0f
#define NW 32      // workgroups per direction in recurrence
#define HSL 16     // hidden units owned per WG (512/32)
#define VCH 256    // viterbi feats LDS chunk (steps)

// ---------------- embedding gather: x[t][:] = emb[sent[t]][:] ----------------
__global__ void k_gather(const int* __restrict__ sent, const float* __restrict__ emb,
                         float* __restrict__ x) {
    int t = blockIdx.x;
    int e4 = threadIdx.x;  // 128 threads * float4 = 512 floats
    const float4* src = (const float4*)(emb + (size_t)sent[t] * EE);
    ((float4*)(x + (size_t)t * EE))[e4] = src[e4];
}

// ------- xg[dir][t][n] = sum_k x[t][k]*w_ih[n][k] + b[n]  (A@B^T GEMM) -------
__global__ __launch_bounds__(256) void k_xgemm(const float* __restrict__ x,
        const float* __restrict__ wf, const float* __restrict__ wb,
        const float* __restrict__ bf, const float* __restrict__ bb,
        float* __restrict__ xg) {
    const int dir = blockIdx.z;
    const float* __restrict__ w    = dir ? wb : wf;
    const float* __restrict__ bias = dir ? bb : bf;
    const int tb = blockIdx.y * 64;
    const int nb = blockIdx.x * 64;
    __shared__ float As[64][17];
    __shared__ float Bs[64][17];
    const int tid = threadIdx.x;
    const int lr = tid >> 2;
    const int lc = (tid & 3) * 4;
    const int ty = tid >> 4;
    const int tx = tid & 15;
    float acc[4][4] = {};
    for (int k0 = 0; k0 < EE; k0 += 16) {
        float4 av = *(const float4*)(x + (size_t)(tb + lr) * EE + k0 + lc);
        float4 bv = *(const float4*)(w + (size_t)(nb + lr) * EE + k0 + lc);
        As[lr][lc+0] = av.x; As[lr][lc+1] = av.y; As[lr][lc+2] = av.z; As[lr][lc+3] = av.w;
        Bs[lr][lc+0] = bv.x; Bs[lr][lc+1] = bv.y; Bs[lr][lc+2] = bv.z; Bs[lr][lc+3] = bv.w;
        __syncthreads();
        #pragma unroll
        for (int kk = 0; kk < 16; ++kk) {
            float a[4], b[4];
            #pragma unroll
            for (int i = 0; i < 4; ++i) a[i] = As[ty*4+i][kk];
            #pragma unroll
            for (int j = 0; j < 4; ++j) b[j] = Bs[tx*4+j][kk];
            #pragma unroll
            for (int i = 0; i < 4; ++i)
                #pragma unroll
                for (int j = 0; j < 4; ++j)
                    acc[i][j] += a[i] * b[j];
        }
        __syncthreads();
    }
    #pragma unroll
    for (int i = 0; i < 4; ++i) {
        float4 o;
        o.x = acc[i][0] + bias[nb + tx*4 + 0];
        o.y = acc[i][1] + bias[nb + tx*4 + 1];
        o.z = acc[i][2] + bias[nb + tx*4 + 2];
        o.w = acc[i][3] + bias[nb + tx*4 + 3];
        *(float4*)(xg + ((size_t)dir*TT + tb + ty*4 + i) * 2048 + nb + tx*4) = o;
    }
}

// ---------------- bidirectional LSTM recurrence ----------------
// grid (NW, 2). WG (wg,dir) owns hidden units [wg*16, wg*16+16) and the 64
// corresponding gate rows; weights live in VGPRs (float4 w[32] per thread).
// Step sync: per-(dir,step) counter, release add / acquire spin; h slices
// published with relaxed agent-scope atomic stores (LLC-coherent across XCDs).
__global__ __launch_bounds__(256, 1) void k_lstm(const float* __restrict__ xg,
        const float* __restrict__ whhf, const float* __restrict__ whhb,
        const float* __restrict__ h0, const float* __restrict__ c0,
        float* __restrict__ hs, int* __restrict__ cnt) {
    const int wg  = blockIdx.x;
    const int dir = blockIdx.y;
    const float* __restrict__ whh = dir ? whhb : whhf;
    const int tid    = threadIdx.x;
    const int lr     = tid >> 2;     // 0..63 local gate row
    const int gate   = lr >> 4;      // 0..3 (i,f,g,o)
    const int within = lr & 15;
    const int seg    = tid & 3;      // 128-wide k segment
    const int hbase  = wg * HSL;
    const int grow   = gate * HDD + hbase + within;  // global gate row

    float4 w[32];
    {
        const float4* wp = (const float4*)(whh + (size_t)grow * HDD + seg * 128);
        #pragma unroll
        for (int i = 0; i < 32; ++i) w[i] = wp[i];
    }

    __shared__ __align__(16) float hbuf[HDD];
    __shared__ float gsum[4][HSL];
    __shared__ float cbuf[HSL];
    if (tid < HSL) cbuf[tid] = c0[dir * HDD + hbase + tid];

    int* myflags = cnt + dir * TT;

    for (int s = 0; s < TT; ++s) {
        const int t = dir ? (TT - 1 - s) : s;
        if (s > 0) {
            if (tid == 0) {
                while (__hip_atomic_load(&myflags[s-1], __ATOMIC_ACQUIRE,
                                         __HIP_MEMORY_SCOPE_AGENT) < NW) {
                    __builtin_amdgcn_s_sleep(1);
                }
            }
            __syncthreads();
            const int tprev = dir ? (t + 1) : (t - 1);
            const float* hsrc = hs + ((size_t)dir * TT + tprev) * HDD;
            for (int i = tid; i < HDD; i += 256)
                hbuf[i] = __hip_atomic_load(&hsrc[i], __ATOMIC_RELAXED,
                                            __HIP_MEMORY_SCOPE_AGENT);
        } else {
            for (int i = tid; i < HDD; i += 256) hbuf[i] = h0[dir * HDD + i];
        }
        const float xv = xg[((size_t)dir * TT + t) * 2048 + grow];
        __syncthreads();

        float acc = 0.f;
        const float4* hp = (const float4*)(hbuf + seg * 128);
        #pragma unroll
        for (int i = 0; i < 32; ++i) {
            float4 hv = hp[i];
            acc += w[i].x * hv.x;
            acc += w[i].y * hv.y;
            acc += w[i].z * hv.z;
            acc += w[i].w * hv.w;
        }
        acc += __shfl_xor(acc, 1);
        acc += __shfl_xor(acc, 2);
        if (seg == 0) gsum[gate][within] = acc + xv;
        __syncthreads();
        if (tid < HSL) {
            const float iv = gsum[0][tid];
            const float fv = gsum[1][tid];
            const float gv = gsum[2][tid];
            const float ov = gsum[3][tid];
            const float ig = 1.f / (1.f + expf(-iv));
            const float fg = 1.f / (1.f + expf(-fv));
            const float gg = tanhf(gv);
            const float og = 1.f / (1.f + expf(-ov));
            const float c = fg * cbuf[tid] + ig * gg;
            cbuf[tid] = c;
            const float h = og * tanhf(c);
            __hip_atomic_store(&hs[((size_t)dir * TT + t) * HDD + hbase + tid], h,
                               __ATOMIC_RELAXED, __HIP_MEMORY_SCOPE_AGENT);
        }
        __syncthreads();
        if (tid == 0)
            __hip_atomic_fetch_add(&myflags[s], 1, __ATOMIC_RELEASE,
                                   __HIP_MEMORY_SCOPE_AGENT);
    }
}

// ------- feats[t][tag] = sum_k concat(hf,hb)[t][k]*W_out[tag][k] + b_out -----
__global__ __launch_bounds__(256) void k_feats(const float* __restrict__ hs,
        const float* __restrict__ Wout, const float* __restrict__ bout,
        float* __restrict__ feats) {
    const int t = blockIdx.x;
    const int tid = threadIdx.x;
    const int tag = tid >> 3;    // 0..31
    const int chunk = tid & 7;   // 8 chunks of 128 k
    const float* __restrict__ hrow = (chunk < 4)
        ? hs + (size_t)t * HDD
        : hs + ((size_t)TT + t) * HDD - 512;
    float acc = 0.f;
    const float4* wp = (const float4*)(Wout + (size_t)tag * 1024 + chunk * 128);
    const float4* hp = (const float4*)(hrow + chunk * 128);
    #pragma unroll
    for (int i = 0; i < 32; ++i) {
        float4 wv = wp[i];
        float4 hv = hp[i];
        acc += wv.x*hv.x + wv.y*hv.y + wv.z*hv.z + wv.w*hv.w;
    }
    __shared__ float red[TAGS][9];
    red[tag][chunk] = acc;
    __syncthreads();
    if (tid < TAGS) {
        float s = bout[tid];
        #pragma unroll
        for (int c = 0; c < 8; ++c) s += red[tid][c];
        feats[(size_t)t * TAGS + tid] = s;
    }
}

// ---------------- Viterbi: single wave, transitions in registers ------------
__global__ __launch_bounds__(64) void k_viterbi(const float* __restrict__ feats,
        const float* __restrict__ trans, unsigned char* __restrict__ bp8,
        float* __restrict__ out) {
    const int lane = threadIdx.x;
    const int n = lane & 31;          // both half-waves duplicate work (benign)
    __shared__ float fvs[TAGS];
    __shared__ float term[TAGS];
    __shared__ __align__(16) float fbuf[VCH * TAGS];
    float tr[TAGS];
    #pragma unroll
    for (int p = 0; p < TAGS; ++p) tr[p] = trans[n * TAGS + p];
    if (lane < TAGS) fvs[lane] = (lane == STARTT) ? 0.f : NEGV;
    __syncthreads();
    for (int c0 = 0; c0 < TT; c0 += VCH) {
        const float4* src = (const float4*)(feats + (size_t)c0 * TAGS);
        float4* dst = (float4*)fbuf;
        for (int i = lane; i < VCH * TAGS / 4; i += 64) dst[i] = src[i];
        __syncthreads();
        for (int lt = 0; lt < VCH; ++lt) {
            const int t = c0 + lt;
            float bv = fvs[0] + tr[0];
            int bi = 0;
            #pragma unroll
            for (int p = 1; p < TAGS; ++p) {
                const float cand = fvs[p] + tr[p];
                if (cand > bv) { bv = cand; bi = p; }  // strict > keeps first-max
            }
            const float nf = bv + fbuf[lt * TAGS + n];
            bp8[(size_t)t * TAGS + n] = (unsigned char)bi;
            __syncthreads();
            fvs[n] = nf;
            __syncthreads();
        }
    }
    if (lane < TAGS) term[lane] = fvs[lane] + trans[STOPP * TAGS + lane];
    __syncthreads();
    if (lane == 0) {
        float bs = term[0]; int best = 0;
        for (int i = 1; i < TAGS; ++i)
            if (term[i] > bs) { bs = term[i]; best = i; }
        out[0] = bs;
        int tag = best;
        for (int t = TT - 1; t >= 0; --t) {
            out[1 + t] = (float)tag;
            tag = bp8[(size_t)t * TAGS + tag];
        }
    }
}

extern "C" void kernel_launch(void* const* d_in, const int* in_sizes, int n_in,
                              void* d_out, int out_size, void* d_ws, size_t ws_size,
                              hipStream_t stream) {
    const int*   sent  = (const int*)  d_in[0];
    const float* emb   = (const float*)d_in[1];
    const float* wihf  = (const float*)d_in[2];
    const float* whhf  = (const float*)d_in[3];
    const float* bfv   = (const float*)d_in[4];
    const float* wihb  = (const float*)d_in[5];
    const float* whhb  = (const float*)d_in[6];
    const float* bbv   = (const float*)d_in[7];
    const float* Wout  = (const float*)d_in[8];
    const float* bout  = (const float*)d_in[9];
    const float* trans = (const float*)d_in[10];
    const float* h0    = (const float*)d_in[11];
    const float* c0    = (const float*)d_in[12];
    float* out = (float*)d_out;

    char* ws = (char*)d_ws;
    float* x     = (float*)(ws);                                  //  4 MiB
    float* xg    = (float*)(ws + ((size_t)4  << 20));             // 32 MiB  [2][T][2048]
    float* hs    = (float*)(ws + ((size_t)36 << 20));             //  8 MiB  [2][T][512]
    float* feats = (float*)(ws + ((size_t)44 << 20));             // 256 KiB [T][32]
    unsigned char* bp8 = (unsigned char*)(ws + ((size_t)44 << 20) + (256u << 10)); // 64 KiB
    int* cnt     = (int*)(ws + ((size_t)44 << 20) + (320u << 10));                 // 16 KiB

    hipMemsetAsync(cnt, 0, 2 * TT * sizeof(int), stream);
    k_gather <<<TT, 128, 0, stream>>>(sent, emb, x);
    k_xgemm  <<<dim3(32, 32, 2), 256, 0, stream>>>(x, wihf, wihb, bfv, bbv, xg);
    k_lstm   <<<dim3(NW, 2), 256, 0, stream>>>(xg, whhf, whhb, h0, c0, hs, cnt);
    k_feats  <<<TT, 256, 0, stream>>>(hs, Wout, bout, feats);
    k_viterbi<<<1, 64, 0, stream>>>(feats, trans, bp8, out);
}

// Round 2
// 6448.228 us; speedup vs baseline: 1.4487x; 1.4487x over previous
//
#include <hip/hip_runtime.h>
#include <math.h>

#define TT 2048
#define EE 512
#define HDD 512
#define TAGS 32
#define STARTT 30
#define STOPP 31
#define NEGV -10000.0f
#define VCH 256    // viterbi feats LDS chunk (steps)
#define SENT 0xFFFFFFFFu   // hs sentinel: -NaN bit pattern, unreachable for finite h

// ---------------- embedding gather: x[t][:] = emb[sent[t]][:] ----------------
__global__ void k_gather(const int* __restrict__ sent, const float* __restrict__ emb,
                         float* __restrict__ x) {
    int t = blockIdx.x;
    int e4 = threadIdx.x;  // 128 threads * float4 = 512 floats
    const float4* src = (const float4*)(emb + (size_t)sent[t] * EE);
    ((float4*)(x + (size_t)t * EE))[e4] = src[e4];
}

// ------- xg[dir][t][n] = sum_k x[t][k]*w_ih[n][k] + b[n]  (A@B^T GEMM) -------
__global__ __launch_bounds__(256) void k_xgemm(const float* __restrict__ x,
        const float* __restrict__ wf, const float* __restrict__ wb,
        const float* __restrict__ bf, const float* __restrict__ bb,
        float* __restrict__ xg) {
    const int dir = blockIdx.z;
    const float* __restrict__ w    = dir ? wb : wf;
    const float* __restrict__ bias = dir ? bb : bf;
    const int tb = blockIdx.y * 64;
    const int nb = blockIdx.x * 64;
    __shared__ float As[64][17];
    __shared__ float Bs[64][17];
    const int tid = threadIdx.x;
    const int lr = tid >> 2;
    const int lc = (tid & 3) * 4;
    const int ty = tid >> 4;
    const int tx = tid & 15;
    float acc[4][4] = {};
    for (int k0 = 0; k0 < EE; k0 += 16) {
        float4 av = *(const float4*)(x + (size_t)(tb + lr) * EE + k0 + lc);
        float4 bv = *(const float4*)(w + (size_t)(nb + lr) * EE + k0 + lc);
        As[lr][lc+0] = av.x; As[lr][lc+1] = av.y; As[lr][lc+2] = av.z; As[lr][lc+3] = av.w;
        Bs[lr][lc+0] = bv.x; Bs[lr][lc+1] = bv.y; Bs[lr][lc+2] = bv.z; Bs[lr][lc+3] = bv.w;
        __syncthreads();
        #pragma unroll
        for (int kk = 0; kk < 16; ++kk) {
            float a[4], b[4];
            #pragma unroll
            for (int i = 0; i < 4; ++i) a[i] = As[ty*4+i][kk];
            #pragma unroll
            for (int j = 0; j < 4; ++j) b[j] = Bs[tx*4+j][kk];
            #pragma unroll
            for (int i = 0; i < 4; ++i)
                #pragma unroll
                for (int j = 0; j < 4; ++j)
                    acc[i][j] += a[i] * b[j];
        }
        __syncthreads();
    }
    #pragma unroll
    for (int i = 0; i < 4; ++i) {
        float4 o;
        o.x = acc[i][0] + bias[nb + tx*4 + 0];
        o.y = acc[i][1] + bias[nb + tx*4 + 1];
        o.z = acc[i][2] + bias[nb + tx*4 + 2];
        o.w = acc[i][3] + bias[nb + tx*4 + 3];
        *(float4*)(xg + ((size_t)dir*TT + tb + ty*4 + i) * 2048 + nb + tx*4) = o;
    }
}

__device__ __forceinline__ float fsig(float x) {
    return __builtin_amdgcn_rcpf(1.f + __expf(-x));
}
__device__ __forceinline__ float ftanh(float x) {
    return 2.f * __builtin_amdgcn_rcpf(1.f + __expf(-2.f * x)) - 1.f;
}

// ---------------- bidirectional LSTM recurrence (wave-autonomous) -----------
// grid (32, 2) x 256. Each WAVE owns 4 hidden units end-to-end:
// lane = unit*16 + gate*4 + seg; weights for its 16 gate-rows live in VGPRs
// (32 float4/lane). No __syncthreads in the step loop; gate combine is
// intra-wave shuffles. Cross-wave dependency is data-flagged: hs is memset to
// 0xFF (NaN bits, unreachable for finite h); consumers poll their 8 h dwords
// with relaxed agent-scope atomic loads until non-sentinel. Producers publish
// h with relaxed agent-scope atomic stores (LLC-coherent across XCDs).
__global__ __launch_bounds__(256, 1) void k_lstm(const float* __restrict__ xg,
        const float* __restrict__ whhf, const float* __restrict__ whhb,
        const float* __restrict__ h0, const float* __restrict__ c0,
        float* __restrict__ hs) {
    const int dir = blockIdx.y;
    const float* __restrict__ whh = dir ? whhb : whhf;
    const int tid    = threadIdx.x;
    const int lane   = tid & 63;
    const int waveid = tid >> 6;
    const int unit   = lane >> 4;        // 0..3
    const int gate   = (lane >> 2) & 3;  // 0..3 (i,f,g,o)
    const int seg    = lane & 3;         // k segment (128 floats)
    const int ubase  = (blockIdx.x * 4 + waveid) * 4;
    const int grow   = gate * HDD + ubase + unit;   // gate-row index

    // weights: w_hh[grow][seg*128 .. +128) -> 32 float4 in VGPRs
    float4 w[32];
    {
        const float4* wp = (const float4*)(whh + (size_t)grow * HDD + seg * 128);
        #pragma unroll
        for (int i = 0; i < 32; ++i) w[i] = wp[i];
    }

    // per-wave padded h staging: 4 segs x 132 floats (132%32=4 -> disjoint banks)
    __shared__ float hsh[4 * 528];
    float* myh = hsh + waveid * 528;

    float c = c0[dir * HDD + ubase + unit];

    // xg prefetch one step ahead
    const int t0 = dir ? (TT - 1) : 0;
    float xvn = xg[((size_t)dir * TT + t0) * 2048 + grow];

    for (int s = 0; s < TT; ++s) {
        const int t = dir ? (TT - 1 - s) : s;
        const float xv = xvn;
        if (s + 1 < TT) {
            const int tn = dir ? (TT - 2 - s) : (s + 1);
            xvn = xg[((size_t)dir * TT + tn) * 2048 + grow];
        }

        float v[8];
        if (s == 0) {
            #pragma unroll
            for (int j = 0; j < 8; ++j) v[j] = h0[dir * HDD + j * 64 + lane];
        } else {
            const int tprev = dir ? (t + 1) : (t - 1);
            const unsigned* hsrc =
                (const unsigned*)(hs + ((size_t)dir * TT + tprev) * HDD);
            unsigned u[8];
            bool ok;
            do {
                #pragma unroll
                for (int j = 0; j < 8; ++j)
                    u[j] = __hip_atomic_load(hsrc + j * 64 + lane,
                                             __ATOMIC_RELAXED, __HIP_MEMORY_SCOPE_AGENT);
                ok = true;
                #pragma unroll
                for (int j = 0; j < 8; ++j) ok &= (u[j] != SENT);
            } while (!ok);
            #pragma unroll
            for (int j = 0; j < 8; ++j) v[j] = __uint_as_float(u[j]);
        }

        // stage into padded LDS (intra-wave only, no barrier needed)
        #pragma unroll
        for (int j = 0; j < 8; ++j) {
            const int l = j * 64 + lane;
            myh[(l >> 7) * 132 + (l & 127)] = v[j];
        }

        // dot over this lane's 128-float k segment
        float acc = 0.f;
        const float4* hp = (const float4*)(myh + seg * 132);
        #pragma unroll
        for (int i = 0; i < 32; ++i) {
            float4 hv = hp[i];
            acc += w[i].x * hv.x;
            acc += w[i].y * hv.y;
            acc += w[i].z * hv.z;
            acc += w[i].w * hv.w;
        }
        // reduce across 4 segs (butterfly -> all lanes of the row have total)
        acc += __shfl_xor(acc, 1);
        acc += __shfl_xor(acc, 2);
        acc += xv;

        // gather i,f,g,o for this lane's unit (intra-wave shuffles)
        const int base = lane & ~15;
        const float iv = __shfl(acc, base + 0);
        const float fv = __shfl(acc, base + 4);
        const float gv = __shfl(acc, base + 8);
        const float ov = __shfl(acc, base + 12);
        c = fsig(fv) * c + fsig(iv) * ftanh(gv);
        const float h = fsig(ov) * ftanh(c);

        if ((lane & 15) == 0)
            __hip_atomic_store(&hs[((size_t)dir * TT + t) * HDD + ubase + unit], h,
                               __ATOMIC_RELAXED, __HIP_MEMORY_SCOPE_AGENT);
    }
}

// ------- feats[t][tag] = sum_k concat(hf,hb)[t][k]*W_out[tag][k] + b_out -----
__global__ __launch_bounds__(256) void k_feats(const float* __restrict__ hs,
        const float* __restrict__ Wout, const float* __restrict__ bout,
        float* __restrict__ feats) {
    const int t = blockIdx.x;
    const int tid = threadIdx.x;
    const int tag = tid >> 3;    // 0..31
    const int chunk = tid & 7;   // 8 chunks of 128 k
    const float* __restrict__ hrow = (chunk < 4)
        ? hs + (size_t)t * HDD
        : hs + ((size_t)TT + t) * HDD - 512;
    float acc = 0.f;
    const float4* wp = (const float4*)(Wout + (size_t)tag * 1024 + chunk * 128);
    const float4* hp = (const float4*)(hrow + chunk * 128);
    #pragma unroll
    for (int i = 0; i < 32; ++i) {
        float4 wv = wp[i];
        float4 hv = hp[i];
        acc += wv.x*hv.x + wv.y*hv.y + wv.z*hv.z + wv.w*hv.w;
    }
    __shared__ float red[TAGS][9];
    red[tag][chunk] = acc;
    __syncthreads();
    if (tid < TAGS) {
        float s = bout[tid];
        #pragma unroll
        for (int c = 0; c < 8; ++c) s += red[tid][c];
        feats[(size_t)t * TAGS + tid] = s;
    }
}

// ---------------- Viterbi: single wave, transitions in registers ------------
__global__ __launch_bounds__(64) void k_viterbi(const float* __restrict__ feats,
        const float* __restrict__ trans, unsigned char* __restrict__ bp8,
        float* __restrict__ out) {
    const int lane = threadIdx.x;
    const int n = lane & 31;          // both half-waves duplicate work (benign)
    __shared__ float fvs[TAGS];
    __shared__ float term[TAGS];
    __shared__ __align__(16) float fbuf[VCH * TAGS];
    float tr[TAGS];
    #pragma unroll
    for (int p = 0; p < TAGS; ++p) tr[p] = trans[n * TAGS + p];
    if (lane < TAGS) fvs[lane] = (lane == STARTT) ? 0.f : NEGV;
    __syncthreads();
    for (int c0 = 0; c0 < TT; c0 += VCH) {
        const float4* src = (const float4*)(feats + (size_t)c0 * TAGS);
        float4* dst = (float4*)fbuf;
        for (int i = lane; i < VCH * TAGS / 4; i += 64) dst[i] = src[i];
        __syncthreads();
        for (int lt = 0; lt < VCH; ++lt) {
            const int t = c0 + lt;
            float bv = fvs[0] + tr[0];
            int bi = 0;
            #pragma unroll
            for (int p = 1; p < TAGS; ++p) {
                const float cand = fvs[p] + tr[p];
                if (cand > bv) { bv = cand; bi = p; }  // strict > keeps first-max
            }
            const float nf = bv + fbuf[lt * TAGS + n];
            bp8[(size_t)t * TAGS + n] = (unsigned char)bi;
            __syncthreads();
            fvs[n] = nf;
            __syncthreads();
        }
    }
    if (lane < TAGS) term[lane] = fvs[lane] + trans[STOPP * TAGS + lane];
    __syncthreads();
    if (lane == 0) {
        float bs = term[0]; int best = 0;
        for (int i = 1; i < TAGS; ++i)
            if (term[i] > bs) { bs = term[i]; best = i; }
        out[0] = bs;
        int tag = best;
        for (int t = TT - 1; t >= 0; --t) {
            out[1 + t] = (float)tag;
            tag = bp8[(size_t)t * TAGS + tag];
        }
    }
}

extern "C" void kernel_launch(void* const* d_in, const int* in_sizes, int n_in,
                              void* d_out, int out_size, void* d_ws, size_t ws_size,
                              hipStream_t stream) {
    const int*   sent  = (const int*)  d_in[0];
    const float* emb   = (const float*)d_in[1];
    const float* wihf  = (const float*)d_in[2];
    const float* whhf  = (const float*)d_in[3];
    const float* bfv   = (const float*)d_in[4];
    const float* wihb  = (const float*)d_in[5];
    const float* whhb  = (const float*)d_in[6];
    const float* bbv   = (const float*)d_in[7];
    const float* Wout  = (const float*)d_in[8];
    const float* bout  = (const float*)d_in[9];
    const float* trans = (const float*)d_in[10];
    const float* h0    = (const float*)d_in[11];
    const float* c0    = (const float*)d_in[12];
    float* out = (float*)d_out;

    char* ws = (char*)d_ws;
    float* x     = (float*)(ws);                                  //  4 MiB
    float* xg    = (float*)(ws + ((size_t)4  << 20));             // 32 MiB  [2][T][2048]
    float* hs    = (float*)(ws + ((size_t)36 << 20));             //  8 MiB  [2][T][512]
    float* feats = (float*)(ws + ((size_t)44 << 20));             // 256 KiB [T][32]
    unsigned char* bp8 = (unsigned char*)(ws + ((size_t)44 << 20) + (256u << 10)); // 64 KiB

    // sentinel-fill hs (0xFF bytes = -NaN pattern; finite h can never equal it)
    hipMemsetAsync(hs, 0xFF, (size_t)2 * TT * HDD * sizeof(float), stream);
    k_gather <<<TT, 128, 0, stream>>>(sent, emb, x);
    k_xgemm  <<<dim3(32, 32, 2), 256, 0, stream>>>(x, wihf, wihb, bfv, bbv, xg);
    k_lstm   <<<dim3(32, 2), 256, 0, stream>>>(xg, whhf, whhb, h0, c0, hs);
    k_feats  <<<TT, 256, 0, stream>>>(hs, Wout, bout, feats);
    k_viterbi<<<1, 64, 0, stream>>>(feats, trans, bp8, out);
}